// Round 15
// baseline (124.520 us; speedup 1.0000x reference)
//
#include <hip/hip_runtime.h>

// Problem constants
#define NB     64      // batch
#define TT     2048    // time
#define INQ    8       // input size
#define CC     2       // channels
#define MM     10      // hidden m
#define ROWP   12      // padded row floats (48 B)
#define MATS   124     // matrix stride in LDS tree (124%32=28)
#define PSTR   20      // skp row stride floats (16B-aligned)
#define SLEN   8       // sequential steps per quad segment
#define SEGS   64      // segments per block (256 thr / 4 lanes)
#define NCHUNK 4       // quarters per chain -> grid 512 = 1 clean round at 2 blocks/CU
#define NCHAIN (NB*CC)
#define NBLK   (NCHAIN*NCHUNK)        // 512
#define WSMAT  120                    // padded floats per ws matrix
#define CTRO   (NBLK*WSMAT)           // counter float offset in ws (61440)

typedef float v2f __attribute__((ext_vector_type(2)));

// Upper-triangle index for (k,j), k<j, into 45-element array
__device__ __forceinline__ constexpr int triIdx(int k, int j) {
    return k * 10 + j - ((k + 1) * (k + 2)) / 2;
}

// Broadcast lane (quad base + SRC)'s value to all 4 lanes of the quad.
template <int SRC>
__device__ __forceinline__ float dpp_qbcast(float v) {
    const int i = __float_as_int(v);
    const int r = __builtin_amdgcn_update_dpp(i, i, SRC * 0x55, 0xF, 0xF, true);
    return __int_as_float(r);
}

// One Taylor row-stream, packed pair of rows: t = S*G; A = t; R += cj*t.
// Row r of S*G depends only on row r of S -> in-place safe (S may alias A).
__device__ __forceinline__ void trow_pk(const float* __restrict__ Tri,
                                        v2f* A, v2f* R, const v2f* S, float cj) {
    v2f t[MM];
    t[0] = -S[1] * Tri[triIdx(0, 1)];
    #pragma unroll
    for (int j = 1; j < MM; ++j) t[j] = S[0] * Tri[triIdx(0, j)];
    #pragma unroll
    for (int k = 1; k < MM; ++k) {
        const v2f a = S[k];
        #pragma unroll
        for (int j = 0; j < MM; ++j) {
            if (k == j) continue;
            if (j == 0 && k == 1) continue;
            if (j > k) t[j] += a * Tri[triIdx(k, j)];
            else       t[j] -= a * Tri[triIdx(j, k)];
        }
    }
    #pragma unroll
    for (int j = 0; j < MM; ++j) { A[j] = t[j]; R[j] += cj * t[j]; }
}

__device__ __forceinline__ void trow_s(const float* __restrict__ Tri,
                                       float* A, float* R, const float* S, float cj) {
    float t[MM];
    t[0] = -S[1] * Tri[triIdx(0, 1)];
    #pragma unroll
    for (int j = 1; j < MM; ++j) t[j] = S[0] * Tri[triIdx(0, j)];
    #pragma unroll
    for (int k = 1; k < MM; ++k) {
        const float a = S[k];
        #pragma unroll
        for (int j = 0; j < MM; ++j) {
            if (k == j) continue;
            if (j == 0 && k == 1) continue;
            if (j > k) t[j] += a * Tri[triIdx(k, j)];
            else       t[j] -= a * Tri[triIdx(j, k)];
        }
    }
    #pragma unroll
    for (int j = 0; j < MM; ++j) { A[j] = t[j]; R[j] += cj * t[j]; }
}

// 2-lane pair combine in LDS: buf[ls] <- buf[ls] * buf[rs] (pq = 5-row half)
__device__ __forceinline__ void pair_combine(float* buf_s, int ls, int rs, int pq) {
    float lrow[5][MM];
    #pragma unroll
    for (int r = 0; r < 5; ++r) {
        const float4* lr = reinterpret_cast<const float4*>(
            &buf_s[ls * MATS + (pq * 5 + r) * ROWP]);
        const float4 a = lr[0], b = lr[1], c4 = lr[2];
        lrow[r][0] = a.x;  lrow[r][1] = a.y;  lrow[r][2] = a.z;  lrow[r][3] = a.w;
        lrow[r][4] = b.x;  lrow[r][5] = b.y;  lrow[r][6] = b.z;  lrow[r][7] = b.w;
        lrow[r][8] = c4.x; lrow[r][9] = c4.y;
    }
    float d[5][MM];
    #pragma unroll
    for (int r = 0; r < 5; ++r)
        #pragma unroll
        for (int j = 0; j < MM; ++j)
            d[r][j] = 0.0f;
    #pragma unroll
    for (int k = 0; k < MM; ++k) {
        const float4* rr = reinterpret_cast<const float4*>(&buf_s[rs * MATS + k * ROWP]);
        const float4 a = rr[0], b = rr[1], c4 = rr[2];
        float rrow[MM];
        rrow[0] = a.x;  rrow[1] = a.y;  rrow[2] = a.z;  rrow[3] = a.w;
        rrow[4] = b.x;  rrow[5] = b.y;  rrow[6] = b.z;  rrow[7] = b.w;
        rrow[8] = c4.x; rrow[9] = c4.y;
        #pragma unroll
        for (int r = 0; r < 5; ++r) {
            const float lv = lrow[r][k];
            #pragma unroll
            for (int j = 0; j < MM; ++j)
                d[r][j] += lv * rrow[j];
        }
    }
    float* dst = &buf_s[ls * MATS + pq * 5 * ROWP];
    #pragma unroll
    for (int r = 0; r < 5; ++r) {
        float4* drow = reinterpret_cast<float4*>(dst + r * ROWP);
        drow[0] = make_float4(d[r][0], d[r][1], d[r][2], d[r][3]);
        drow[1] = make_float4(d[r][4], d[r][5], d[r][6], d[r][7]);
        drow[2] = make_float4(d[r][8], d[r][9], 0.0f, 0.0f);
    }
}

// r14 serial kernel (best: 60.7 µs, VGPR 152, no spills, KTAY=5 accuracy
// floor) + r10's proven last-block combine fused at the tail (saves the
// ~6 µs K2 dispatch; the remaining ~42 µs total-minus-serial is fixed
// harness overhead, measured invariant across 9 configs).
__global__ __launch_bounds__(256)
void dev_serial(const float* __restrict__ x,
                const float* __restrict__ A,
                float* __restrict__ ws,
                float* __restrict__ out)
{
    __shared__ __align__(16) float skp_s[24 * PSTR];    // 1920 B pair-interleaved
    __shared__ __align__(16) float buf_s[SEGS * MATS];  // 31744 B tree buffer
    __shared__ int last_s;

    const int tid   = threadIdx.x;
    const int chain = blockIdx.x >> 2;   // / NCHUNK
    const int qt    = blockIdx.x & 3;
    const int n     = chain >> 1;        // / CC
    const int c     = chain & 1;

    // skp[p][ip] = v2f{ sktri[2p][ip], sktri[2p+1][ip] }, rows >=45 zero.
    for (int e = tid; e < 24 * 16; e += 256) {
        const int p   = e >> 4;
        const int rem = e & 15;
        const int ip  = rem >> 1;
        const int h   = rem & 1;
        const int t   = 2 * p + h;
        float v = 0.0f;
        if (t < 45) {
            int k = 0, r2 = t;
            while (r2 >= 9 - k) { r2 -= (9 - k); ++k; }
            const int j = k + 1 + r2;
            const float* Ab = A + (size_t)(c * INQ + ip) * (MM * MM);
            v = Ab[k * MM + j] - Ab[j * MM + k];
        }
        skp_s[p * PSTR + 2 * ip + h] = v;
    }
    for (int p = tid; p < 24; p += 256) {
        skp_s[p * PSTR + 16] = 0.0f; skp_s[p * PSTR + 17] = 0.0f;
        skp_s[p * PSTR + 18] = 0.0f; skp_s[p * PSTR + 19] = 0.0f;
    }
    __syncthreads();

    const int seg = tid >> 2;
    const int q   = tid & 3;                        // lane within quad
    const int p0  = (q < 2) ? 3 * q : (q == 2 ? 6 : 8);  // packed pair rows
    const int sr  = (q < 2) ? (3 * q + 2) : 9;      // scalar row (dummy on q>=2)
    const bool hasS = (q < 2);

    v2f   R01[MM];
    float R2[MM];
    #pragma unroll
    for (int j = 0; j < MM; ++j) {
        R01[j] = (v2f){ (j == p0) ? 1.0f : 0.0f, (j == p0 + 1) ? 1.0f : 0.0f };
        R2[j]  = (j == sr) ? 1.0f : 0.0f;
    }

    const float* xb = x + (size_t)n * TT * INQ;
    const int t0 = qt * (SEGS * SLEN) + seg * SLEN;   // max t0+7 = 2047

    // Pipelined x
    float4 cur0, cur1, nxt0, nxt1;
    {
        const float4* p = reinterpret_cast<const float4*>(xb + (size_t)t0 * INQ);
        cur0 = p[0]; cur1 = p[1];
        int t1 = t0 + 1; if (t1 > TT - 1) t1 = TT - 1;
        const float4* pn = reinterpret_cast<const float4*>(xb + (size_t)t1 * INQ);
        nxt0 = pn[0]; nxt1 = pn[1];
    }

    #pragma unroll 1
    for (int s = 0; s < SLEN; ++s) {
        float dx[INQ];
        dx[0] = nxt0.x - cur0.x; dx[1] = nxt0.y - cur0.y;
        dx[2] = nxt0.z - cur0.z; dx[3] = nxt0.w - cur0.w;
        dx[4] = nxt1.x - cur1.x; dx[5] = nxt1.y - cur1.y;
        dx[6] = nxt1.z - cur1.z; dx[7] = nxt1.w - cur1.w;
        cur0 = nxt0; cur1 = nxt1;
        {
            int t2 = t0 + s + 2; if (t2 > TT - 1) t2 = TT - 1;
            const float4* pn = reinterpret_cast<const float4*>(xb + (size_t)t2 * INQ);
            nxt0 = pn[0]; nxt1 = pn[1];
        }

        // Packed tv: tvp[pp] = (tri[12q+2pp], tri[12q+2pp+1])
        v2f tvp[6];
        #pragma unroll
        for (int pp = 0; pp < 6; ++pp) {
            const v2f* sp = reinterpret_cast<const v2f*>(&skp_s[(6 * q + pp) * PSTR]);
            v2f acc = dx[0] * sp[0];
            #pragma unroll
            for (int ip = 1; ip < INQ; ++ip)
                acc += dx[ip] * sp[ip];
            tvp[pp] = acc;
        }
        float tv[12];
        #pragma unroll
        for (int pp = 0; pp < 6; ++pp) { tv[2 * pp] = tvp[pp].x; tv[2 * pp + 1] = tvp[pp].y; }

        // Assemble Tri[45] per-lane via DPP quad broadcast
        float Tri[45];
        #define TRIFILL(U) Tri[U] = dpp_qbcast<(U) / 12>(tv[(U) % 12]);
        TRIFILL(0)  TRIFILL(1)  TRIFILL(2)  TRIFILL(3)  TRIFILL(4)
        TRIFILL(5)  TRIFILL(6)  TRIFILL(7)  TRIFILL(8)  TRIFILL(9)
        TRIFILL(10) TRIFILL(11) TRIFILL(12) TRIFILL(13) TRIFILL(14)
        TRIFILL(15) TRIFILL(16) TRIFILL(17) TRIFILL(18) TRIFILL(19)
        TRIFILL(20) TRIFILL(21) TRIFILL(22) TRIFILL(23) TRIFILL(24)
        TRIFILL(25) TRIFILL(26) TRIFILL(27) TRIFILL(28) TRIFILL(29)
        TRIFILL(30) TRIFILL(31) TRIFILL(32) TRIFILL(33) TRIFILL(34)
        TRIFILL(35) TRIFILL(36) TRIFILL(37) TRIFILL(38) TRIFILL(39)
        TRIFILL(40) TRIFILL(41) TRIFILL(42) TRIFILL(43) TRIFILL(44)
        #undef TRIFILL

        // Unnormalized ascending Horner, KTAY=5 (accuracy floor):
        // A_j = A_{j-1}*G; R += (1/j!)*A_j
        v2f   A01[MM];
        float A2[MM];
        trow_pk(Tri, A01, R01, R01, 1.0f);
        trow_s (Tri, A2,  R2,  R2,  1.0f);
        trow_pk(Tri, A01, R01, A01, 0.5f);
        trow_s (Tri, A2,  R2,  A2,  0.5f);
        trow_pk(Tri, A01, R01, A01, 0.16666667f);
        trow_s (Tri, A2,  R2,  A2,  0.16666667f);
        trow_pk(Tri, A01, R01, A01, 0.041666668f);
        trow_s (Tri, A2,  R2,  A2,  0.041666668f);
        trow_pk(Tri, A01, R01, A01, 0.0083333338f);
        trow_s (Tri, A2,  R2,  A2,  0.0083333338f);
    }

    // Store segment product: packed pair rows from all lanes, scalar from q<2
    {
        float* dst = &buf_s[seg * MATS];
        float4* d0 = reinterpret_cast<float4*>(dst + p0 * ROWP);
        d0[0] = make_float4(R01[0].x, R01[1].x, R01[2].x, R01[3].x);
        d0[1] = make_float4(R01[4].x, R01[5].x, R01[6].x, R01[7].x);
        d0[2] = make_float4(R01[8].x, R01[9].x, 0.0f, 0.0f);
        float4* d1 = reinterpret_cast<float4*>(dst + (p0 + 1) * ROWP);
        d1[0] = make_float4(R01[0].y, R01[1].y, R01[2].y, R01[3].y);
        d1[1] = make_float4(R01[4].y, R01[5].y, R01[6].y, R01[7].y);
        d1[2] = make_float4(R01[8].y, R01[9].y, 0.0f, 0.0f);
        if (hasS) {
            float4* d2 = reinterpret_cast<float4*>(dst + sr * ROWP);
            d2[0] = make_float4(R2[0], R2[1], R2[2], R2[3]);
            d2[1] = make_float4(R2[4], R2[5], R2[6], R2[7]);
            d2[2] = make_float4(R2[8], R2[9], 0.0f, 0.0f);
        }
    }
    __syncthreads();

    // Pair-style dyadic tree, full 6 levels (64 -> 1 product at slot 0)
    #pragma unroll 1
    for (int span = 2; span <= SEGS; span <<= 1) {
        const int np = SEGS / span;
        if (tid < 2 * np) {
            const int pr = tid >> 1;
            const int pq = tid & 1;
            pair_combine(buf_s, pr * span, pr * span + (span >> 1), pq);
        }
        __syncthreads();
    }

    // Chunk product -> ws, padded 120 floats at (chain*NCHUNK + qt)
    if (tid < 30) {
        const float4 v = reinterpret_cast<const float4*>(buf_s)[tid];
        reinterpret_cast<float4*>(ws)[((size_t)chain * NCHUNK + qt) * 30 + tid] = v;
    }
    __syncthreads();

    // Last-block combine (r10's proven device-scope release/acquire pattern)
    unsigned int* ctr = reinterpret_cast<unsigned int*>(ws + CTRO);
    if (tid == 0) {
        __threadfence();                       // release: ws product visible
        const unsigned int old = atomicAdd(ctr, 1u);
        last_s = (old == NBLK - 1) ? 1 : 0;
    }
    __syncthreads();
    if (last_s) {
        __threadfence();                       // acquire: see all blocks' ws
        // 2 lanes per chain: lane pq owns rows pq*5..pq*5+4
        const int ch = tid >> 1;
        const int pq = tid & 1;
        const float* base = ws + (size_t)ch * NCHUNK * WSMAT;

        float Rr[5][MM];
        #pragma unroll
        for (int r = 0; r < 5; ++r) {
            const float4* lr = reinterpret_cast<const float4*>(
                base + (pq * 5 + r) * ROWP);
            const float4 a = lr[0], b = lr[1], c4 = lr[2];
            Rr[r][0] = a.x;  Rr[r][1] = a.y;  Rr[r][2] = a.z;  Rr[r][3] = a.w;
            Rr[r][4] = b.x;  Rr[r][5] = b.y;  Rr[r][6] = b.z;  Rr[r][7] = b.w;
            Rr[r][8] = c4.x; Rr[r][9] = c4.y;
        }

        #pragma unroll 1
        for (int ck = 1; ck < NCHUNK; ++ck) {
            const float* B = base + ck * WSMAT;
            float d[5][MM];
            #pragma unroll
            for (int r = 0; r < 5; ++r)
                #pragma unroll
                for (int j = 0; j < MM; ++j)
                    d[r][j] = 0.0f;
            #pragma unroll
            for (int k = 0; k < MM; ++k) {
                const float4* br = reinterpret_cast<const float4*>(B + k * ROWP);
                const float4 a = br[0], b = br[1], c4 = br[2];
                float brow[MM];
                brow[0] = a.x;  brow[1] = a.y;  brow[2] = a.z;  brow[3] = a.w;
                brow[4] = b.x;  brow[5] = b.y;  brow[6] = b.z;  brow[7] = b.w;
                brow[8] = c4.x; brow[9] = c4.y;
                #pragma unroll
                for (int r = 0; r < 5; ++r) {
                    const float rv = Rr[r][k];
                    #pragma unroll
                    for (int j = 0; j < MM; ++j)
                        d[r][j] += rv * brow[j];
                }
            }
            #pragma unroll
            for (int r = 0; r < 5; ++r)
                #pragma unroll
                for (int j = 0; j < MM; ++j)
                    Rr[r][j] = d[r][j];
        }

        #pragma unroll
        for (int r = 0; r < 5; ++r)
            #pragma unroll
            for (int j = 0; j < MM; ++j)
                out[(size_t)ch * 100 + (pq * 5 + r) * 10 + j] = Rr[r][j];
    }
}

extern "C" void kernel_launch(void* const* d_in, const int* in_sizes, int n_in,
                              void* d_out, int out_size, void* d_ws, size_t ws_size,
                              hipStream_t stream) {
    (void)in_sizes; (void)n_in; (void)out_size; (void)ws_size;
    const float* x = (const float*)d_in[0];  // (64, 2048, 8)
    const float* A = (const float*)d_in[1];  // (2, 8, 10, 10)
    float* out = (float*)d_out;              // (64, 2, 10, 10)
    float* ws  = (float*)d_ws;               // 512 mats * 480 B + 4 B counter

    // zero the completion counter (ws is re-poisoned 0xAA before every call)
    hipMemsetAsync((char*)d_ws + CTRO * sizeof(float), 0, sizeof(unsigned int), stream);
    dev_serial<<<dim3(NBLK), dim3(256), 0, stream>>>(x, A, ws, out);
}

// Round 16
// 109.891 us; speedup vs baseline: 1.1331x; 1.1331x over previous
//
#include <hip/hip_runtime.h>

// Problem constants
#define NB     64      // batch
#define TT     2048    // time
#define INQ    8       // input size
#define CC     2       // channels
#define MM     10      // hidden m
#define ROWP   12      // padded row floats (48 B)
#define MATS   124     // matrix stride in LDS tree (124%32=28)
#define PSTR   20      // skp row stride floats (16B-aligned)
#define SLEN   8       // sequential steps per quad segment
#define SEGS   64      // segments per block (256 thr / 4 lanes)
#define NCHUNK 4       // quarters per chain -> grid 512 = 1 clean round at 2 blocks/CU
#define NCHAIN (NB*CC)

typedef float v2f __attribute__((ext_vector_type(2)));

// Upper-triangle index for (k,j), k<j, into 45-element array
__device__ __forceinline__ constexpr int triIdx(int k, int j) {
    return k * 10 + j - ((k + 1) * (k + 2)) / 2;
}

// Broadcast lane (quad base + SRC)'s value to all 4 lanes of the quad.
template <int SRC>
__device__ __forceinline__ float dpp_qbcast(float v) {
    const int i = __float_as_int(v);
    const int r = __builtin_amdgcn_update_dpp(i, i, SRC * 0x55, 0xF, 0xF, true);
    return __int_as_float(r);
}

// One Taylor row-stream, packed pair of rows: t = S*G; A = t; R += cj*t.
// Row r of S*G depends only on row r of S -> in-place safe (S may alias A).
__device__ __forceinline__ void trow_pk(const float* __restrict__ Tri,
                                        v2f* A, v2f* R, const v2f* S, float cj) {
    v2f t[MM];
    t[0] = -S[1] * Tri[triIdx(0, 1)];
    #pragma unroll
    for (int j = 1; j < MM; ++j) t[j] = S[0] * Tri[triIdx(0, j)];
    #pragma unroll
    for (int k = 1; k < MM; ++k) {
        const v2f a = S[k];
        #pragma unroll
        for (int j = 0; j < MM; ++j) {
            if (k == j) continue;
            if (j == 0 && k == 1) continue;
            if (j > k) t[j] += a * Tri[triIdx(k, j)];
            else       t[j] -= a * Tri[triIdx(j, k)];
        }
    }
    #pragma unroll
    for (int j = 0; j < MM; ++j) { A[j] = t[j]; R[j] += cj * t[j]; }
}

__device__ __forceinline__ void trow_s(const float* __restrict__ Tri,
                                       float* A, float* R, const float* S, float cj) {
    float t[MM];
    t[0] = -S[1] * Tri[triIdx(0, 1)];
    #pragma unroll
    for (int j = 1; j < MM; ++j) t[j] = S[0] * Tri[triIdx(0, j)];
    #pragma unroll
    for (int k = 1; k < MM; ++k) {
        const float a = S[k];
        #pragma unroll
        for (int j = 0; j < MM; ++j) {
            if (k == j) continue;
            if (j == 0 && k == 1) continue;
            if (j > k) t[j] += a * Tri[triIdx(k, j)];
            else       t[j] -= a * Tri[triIdx(j, k)];
        }
    }
    #pragma unroll
    for (int j = 0; j < MM; ++j) { A[j] = t[j]; R[j] += cj * t[j]; }
}

// 2-lane pair combine: buf[ls] <- buf[ls] * buf[rs] (pq = which 5-row half)
__device__ __forceinline__ void pair_combine(float* buf_s, int ls, int rs, int pq) {
    float lrow[5][MM];
    #pragma unroll
    for (int r = 0; r < 5; ++r) {
        const float4* lr = reinterpret_cast<const float4*>(
            &buf_s[ls * MATS + (pq * 5 + r) * ROWP]);
        const float4 a = lr[0], b = lr[1], c4 = lr[2];
        lrow[r][0] = a.x;  lrow[r][1] = a.y;  lrow[r][2] = a.z;  lrow[r][3] = a.w;
        lrow[r][4] = b.x;  lrow[r][5] = b.y;  lrow[r][6] = b.z;  lrow[r][7] = b.w;
        lrow[r][8] = c4.x; lrow[r][9] = c4.y;
    }
    float d[5][MM];
    #pragma unroll
    for (int r = 0; r < 5; ++r)
        #pragma unroll
        for (int j = 0; j < MM; ++j)
            d[r][j] = 0.0f;
    #pragma unroll
    for (int k = 0; k < MM; ++k) {
        const float4* rr = reinterpret_cast<const float4*>(&buf_s[rs * MATS + k * ROWP]);
        const float4 a = rr[0], b = rr[1], c4 = rr[2];
        float rrow[MM];
        rrow[0] = a.x;  rrow[1] = a.y;  rrow[2] = a.z;  rrow[3] = a.w;
        rrow[4] = b.x;  rrow[5] = b.y;  rrow[6] = b.z;  rrow[7] = b.w;
        rrow[8] = c4.x; rrow[9] = c4.y;
        #pragma unroll
        for (int r = 0; r < 5; ++r) {
            const float lv = lrow[r][k];
            #pragma unroll
            for (int j = 0; j < MM; ++j)
                d[r][j] += lv * rrow[j];
        }
    }
    float* dst = &buf_s[ls * MATS + pq * 5 * ROWP];
    #pragma unroll
    for (int r = 0; r < 5; ++r) {
        float4* drow = reinterpret_cast<float4*>(dst + r * ROWP);
        drow[0] = make_float4(d[r][0], d[r][1], d[r][2], d[r][3]);
        drow[1] = make_float4(d[r][4], d[r][5], d[r][6], d[r][7]);
        drow[2] = make_float4(d[r][8], d[r][9], 0.0f, 0.0f);
    }
}

// r14 configuration — measured best (108.9 µs total; serial 60.7 µs,
// VGPR 152, zero spills). Structural constraints, all HW-verified over
// rounds 1-15: (1) occupancy pinned at 2 waves/SIMD — VGPR cliffs at
// {64,128,256}; every attempt to cross (launch_bounds hints r4/r8,
// live-set cuts r11, pair-split r13) spilled or regressed. (2) KTAY=5 is
// the series accuracy floor (absmax 7.8e-3 vs 19.5e-3 threshold; term-5
// removal would add ~7e-2). (3) ~42-48 µs of total is fixed harness
// overhead, invariant across 9 configs incl. single-kernel fusion (r10,
// r15 — fusion regressed, reverted). (4) pk-packing gains only issue
// density (~9%), not FLOP rate — CDNA4 fp32 peak is scalar-equal.
__global__ __launch_bounds__(256)
void dev_serial(const float* __restrict__ x,
                const float* __restrict__ A,
                float* __restrict__ ws)
{
    __shared__ __align__(16) float skp_s[24 * PSTR];    // 1920 B pair-interleaved
    __shared__ __align__(16) float buf_s[SEGS * MATS];  // 31744 B tree buffer

    const int tid   = threadIdx.x;
    const int chain = blockIdx.x >> 2;   // / NCHUNK
    const int qt    = blockIdx.x & 3;
    const int n     = chain >> 1;        // / CC
    const int c     = chain & 1;

    // skp[p][ip] = v2f{ sktri[2p][ip], sktri[2p+1][ip] }, rows >=45 zero.
    for (int e = tid; e < 24 * 16; e += 256) {
        const int p   = e >> 4;
        const int rem = e & 15;
        const int ip  = rem >> 1;
        const int h   = rem & 1;
        const int t   = 2 * p + h;
        float v = 0.0f;
        if (t < 45) {
            int k = 0, r2 = t;
            while (r2 >= 9 - k) { r2 -= (9 - k); ++k; }
            const int j = k + 1 + r2;
            const float* Ab = A + (size_t)(c * INQ + ip) * (MM * MM);
            v = Ab[k * MM + j] - Ab[j * MM + k];
        }
        skp_s[p * PSTR + 2 * ip + h] = v;
    }
    for (int p = tid; p < 24; p += 256) {
        skp_s[p * PSTR + 16] = 0.0f; skp_s[p * PSTR + 17] = 0.0f;
        skp_s[p * PSTR + 18] = 0.0f; skp_s[p * PSTR + 19] = 0.0f;
    }
    __syncthreads();

    const int seg = tid >> 2;
    const int q   = tid & 3;                        // lane within quad
    const int p0  = (q < 2) ? 3 * q : (q == 2 ? 6 : 8);  // packed pair rows
    const int sr  = (q < 2) ? (3 * q + 2) : 9;      // scalar row (dummy on q>=2)
    const bool hasS = (q < 2);

    v2f   R01[MM];
    float R2[MM];
    #pragma unroll
    for (int j = 0; j < MM; ++j) {
        R01[j] = (v2f){ (j == p0) ? 1.0f : 0.0f, (j == p0 + 1) ? 1.0f : 0.0f };
        R2[j]  = (j == sr) ? 1.0f : 0.0f;
    }

    const float* xb = x + (size_t)n * TT * INQ;
    const int t0 = qt * (SEGS * SLEN) + seg * SLEN;   // max t0+7 = 2047

    // Pipelined x
    float4 cur0, cur1, nxt0, nxt1;
    {
        const float4* p = reinterpret_cast<const float4*>(xb + (size_t)t0 * INQ);
        cur0 = p[0]; cur1 = p[1];
        int t1 = t0 + 1; if (t1 > TT - 1) t1 = TT - 1;
        const float4* pn = reinterpret_cast<const float4*>(xb + (size_t)t1 * INQ);
        nxt0 = pn[0]; nxt1 = pn[1];
    }

    #pragma unroll 1
    for (int s = 0; s < SLEN; ++s) {
        float dx[INQ];
        dx[0] = nxt0.x - cur0.x; dx[1] = nxt0.y - cur0.y;
        dx[2] = nxt0.z - cur0.z; dx[3] = nxt0.w - cur0.w;
        dx[4] = nxt1.x - cur1.x; dx[5] = nxt1.y - cur1.y;
        dx[6] = nxt1.z - cur1.z; dx[7] = nxt1.w - cur1.w;
        cur0 = nxt0; cur1 = nxt1;
        {
            int t2 = t0 + s + 2; if (t2 > TT - 1) t2 = TT - 1;
            const float4* pn = reinterpret_cast<const float4*>(xb + (size_t)t2 * INQ);
            nxt0 = pn[0]; nxt1 = pn[1];
        }

        // Packed tv: tvp[pp] = (tri[12q+2pp], tri[12q+2pp+1])
        v2f tvp[6];
        #pragma unroll
        for (int pp = 0; pp < 6; ++pp) {
            const v2f* sp = reinterpret_cast<const v2f*>(&skp_s[(6 * q + pp) * PSTR]);
            v2f acc = dx[0] * sp[0];
            #pragma unroll
            for (int ip = 1; ip < INQ; ++ip)
                acc += dx[ip] * sp[ip];
            tvp[pp] = acc;
        }
        float tv[12];
        #pragma unroll
        for (int pp = 0; pp < 6; ++pp) { tv[2 * pp] = tvp[pp].x; tv[2 * pp + 1] = tvp[pp].y; }

        // Assemble Tri[45] per-lane via DPP quad broadcast
        float Tri[45];
        #define TRIFILL(U) Tri[U] = dpp_qbcast<(U) / 12>(tv[(U) % 12]);
        TRIFILL(0)  TRIFILL(1)  TRIFILL(2)  TRIFILL(3)  TRIFILL(4)
        TRIFILL(5)  TRIFILL(6)  TRIFILL(7)  TRIFILL(8)  TRIFILL(9)
        TRIFILL(10) TRIFILL(11) TRIFILL(12) TRIFILL(13) TRIFILL(14)
        TRIFILL(15) TRIFILL(16) TRIFILL(17) TRIFILL(18) TRIFILL(19)
        TRIFILL(20) TRIFILL(21) TRIFILL(22) TRIFILL(23) TRIFILL(24)
        TRIFILL(25) TRIFILL(26) TRIFILL(27) TRIFILL(28) TRIFILL(29)
        TRIFILL(30) TRIFILL(31) TRIFILL(32) TRIFILL(33) TRIFILL(34)
        TRIFILL(35) TRIFILL(36) TRIFILL(37) TRIFILL(38) TRIFILL(39)
        TRIFILL(40) TRIFILL(41) TRIFILL(42) TRIFILL(43) TRIFILL(44)
        #undef TRIFILL

        // Unnormalized ascending Horner, KTAY=5 (accuracy floor):
        // A_j = A_{j-1}*G; R += (1/j!)*A_j
        v2f   A01[MM];
        float A2[MM];
        trow_pk(Tri, A01, R01, R01, 1.0f);
        trow_s (Tri, A2,  R2,  R2,  1.0f);
        trow_pk(Tri, A01, R01, A01, 0.5f);
        trow_s (Tri, A2,  R2,  A2,  0.5f);
        trow_pk(Tri, A01, R01, A01, 0.16666667f);
        trow_s (Tri, A2,  R2,  A2,  0.16666667f);
        trow_pk(Tri, A01, R01, A01, 0.041666668f);
        trow_s (Tri, A2,  R2,  A2,  0.041666668f);
        trow_pk(Tri, A01, R01, A01, 0.0083333338f);
        trow_s (Tri, A2,  R2,  A2,  0.0083333338f);
    }

    // Store segment product: packed pair rows from all lanes, scalar from q<2
    {
        float* dst = &buf_s[seg * MATS];
        float4* d0 = reinterpret_cast<float4*>(dst + p0 * ROWP);
        d0[0] = make_float4(R01[0].x, R01[1].x, R01[2].x, R01[3].x);
        d0[1] = make_float4(R01[4].x, R01[5].x, R01[6].x, R01[7].x);
        d0[2] = make_float4(R01[8].x, R01[9].x, 0.0f, 0.0f);
        float4* d1 = reinterpret_cast<float4*>(dst + (p0 + 1) * ROWP);
        d1[0] = make_float4(R01[0].y, R01[1].y, R01[2].y, R01[3].y);
        d1[1] = make_float4(R01[4].y, R01[5].y, R01[6].y, R01[7].y);
        d1[2] = make_float4(R01[8].y, R01[9].y, 0.0f, 0.0f);
        if (hasS) {
            float4* d2 = reinterpret_cast<float4*>(dst + sr * ROWP);
            d2[0] = make_float4(R2[0], R2[1], R2[2], R2[3]);
            d2[1] = make_float4(R2[4], R2[5], R2[6], R2[7]);
            d2[2] = make_float4(R2[8], R2[9], 0.0f, 0.0f);
        }
    }
    __syncthreads();

    // Pair-style dyadic tree, full 6 levels (64 -> 1 product at slot 0)
    #pragma unroll 1
    for (int span = 2; span <= SEGS; span <<= 1) {
        const int np = SEGS / span;
        if (tid < 2 * np) {
            const int pr = tid >> 1;
            const int pq = tid & 1;
            pair_combine(buf_s, pr * span, pr * span + (span >> 1), pq);
        }
        __syncthreads();
    }

    // Chunk product -> ws, padded 120 floats at (chain*NCHUNK + qt)
    if (tid < 30) {
        const float4 v = reinterpret_cast<const float4*>(buf_s)[tid];
        reinterpret_cast<float4*>(ws)[((size_t)chain * NCHUNK + qt) * 30 + tid] = v;
    }
}

// K2: one block per chain; combine its 4 chunk products (time order)
__global__ __launch_bounds__(256)
void dev_tree4(const float* __restrict__ ws, float* __restrict__ out)
{
    __shared__ __align__(16) float buf_s[4 * MATS];
    const int tid   = threadIdx.x;
    const int chain = blockIdx.x;

    if (tid < 120) {
        const int m  = tid / 30;
        const int o4 = tid - m * 30;
        const float4 v = reinterpret_cast<const float4*>(ws)[((size_t)chain * 4 + m) * 30 + o4];
        reinterpret_cast<float4*>(&buf_s[m * MATS])[o4] = v;
    }
    __syncthreads();

    if (tid < 4)
        pair_combine(buf_s, (tid >> 1) * 2, (tid >> 1) * 2 + 1, tid & 1);
    __syncthreads();
    if (tid < 2)
        pair_combine(buf_s, 0, 2, tid);
    __syncthreads();

    if (tid < 100) {
        const int i = tid / 10;
        const int j = tid - i * 10;
        out[(size_t)chain * 100 + tid] = buf_s[i * ROWP + j];
    }
}

extern "C" void kernel_launch(void* const* d_in, const int* in_sizes, int n_in,
                              void* d_out, int out_size, void* d_ws, size_t ws_size,
                              hipStream_t stream) {
    (void)in_sizes; (void)n_in; (void)out_size; (void)ws_size;
    const float* x = (const float*)d_in[0];  // (64, 2048, 8)
    const float* A = (const float*)d_in[1];  // (2, 8, 10, 10)
    float* out = (float*)d_out;              // (64, 2, 10, 10)
    float* ws  = (float*)d_ws;               // 512 mats * 480 B = 245,760 B

    dev_serial<<<dim3(NCHAIN * NCHUNK), dim3(256), 0, stream>>>(x, A, ws);
    dev_tree4<<<dim3(NCHAIN), dim3(256), 0, stream>>>(ws, out);
}